// Round 1
// baseline (414.829 us; speedup 1.0000x reference)
//
#include <hip/hip_runtime.h>
#include <cstdint>
#include <cstddef>

typedef _Float16 f16;
typedef f16 f16x8 __attribute__((ext_vector_type(8)));
typedef float f32x4 __attribute__((ext_vector_type(4)));

#define B_ROWS 65536
#define NT_BRANCH 1030   // worst-case branch tiles: 1024 + 6 bins' padding
#define NT_SPEED 1024

// ---------------- ws layout (all offsets 256B-aligned) ----------------
constexpr size_t OFF_SF16   = 0;
constexpr size_t SZ_SF16    = (size_t)B_ROWS * 128 * 2;        // 16,777,216
constexpr size_t OFF_SIW2T  = OFF_SF16 + SZ_SF16;
constexpr size_t SZ_SIW2T   = (size_t)128 * 256 * 2;           // 65,536
constexpr size_t OFF_BW1T   = OFF_SIW2T + SZ_SIW2T;
constexpr size_t SZ_BW1T    = (size_t)6 * 256 * 640 * 2;       // 1,966,080
constexpr size_t OFF_BW2T   = OFF_BW1T + SZ_BW1T;
constexpr size_t SZ_BW2T    = (size_t)6 * 256 * 256 * 2;       // 786,432
constexpr size_t OFF_SOW1T  = OFF_BW2T + SZ_BW2T;
constexpr size_t SZ_SOW1T   = (size_t)256 * 640 * 2;           // 327,680
constexpr size_t OFF_SOW2T  = OFF_SOW1T + SZ_SOW1T;
constexpr size_t SZ_SOW2T   = (size_t)256 * 256 * 2;           // 131,072
constexpr size_t OFF_COUNTS = OFF_SOW2T + SZ_SOW2T;            // 20,054,016
constexpr size_t OFF_CURSORS= OFF_COUNTS + 256;
constexpr size_t OFF_BINBASE= OFF_CURSORS + 256;
constexpr size_t OFF_TILECMD= OFF_BINBASE + 256;
constexpr size_t OFF_PERM   = OFF_TILECMD + 4352;              // 1030*4 -> pad
constexpr size_t WS_NEEDED  = OFF_PERM + (size_t)NT_BRANCH * 64 * 4;

// ---------------- prep: transpose-cast weights + init sort scratch ----------------
// fp32 [R][C] row-major -> f16 [C][R] row-major (W^T) so MFMA B-frags are
// 16B-contiguous per lane. Tail blocks init perm=-1 and zero counters.
__global__ void prep_kernel(const float* __restrict__ siW2,
                            const float* __restrict__ bW1,
                            const float* __restrict__ bW2,
                            const float* __restrict__ soW1,
                            const float* __restrict__ soW2,
                            f16* __restrict__ siW2T, f16* __restrict__ bW1T,
                            f16* __restrict__ bW2T, f16* __restrict__ soW1T,
                            f16* __restrict__ soW2T,
                            int* __restrict__ counts, int* __restrict__ cursors,
                            int* __restrict__ perm)
{
    const int bx = blockIdx.x;
    const int tx = threadIdx.x, ty = threadIdx.y;
    if (bx >= 1600) {
        const int tid = ty * 32 + tx;
        const int ib = bx - 1600;
        const int idx = ib * 256 + tid;
        if (idx < NT_BRANCH * 64) perm[idx] = -1;
        if (ib == 0 && tid < 6) { counts[tid] = 0; cursors[tid] = 0; }
        return;
    }
    const float* in; f16* out; int R, C, lb;
    if (bx < 960)       { int m = bx / 160;        lb = bx - m * 160;      in = bW1 + (size_t)m * 640 * 256; out = bW1T + (size_t)m * 640 * 256; R = 640; C = 256; }
    else if (bx < 1344) { int m = (bx - 960) / 64; lb = (bx - 960) - m * 64; in = bW2 + (size_t)m * 256 * 256; out = bW2T + (size_t)m * 256 * 256; R = 256; C = 256; }
    else if (bx < 1504) { lb = bx - 1344; in = soW1; out = soW1T; R = 640; C = 256; }
    else if (bx < 1568) { lb = bx - 1504; in = soW2; out = soW2T; R = 256; C = 256; }
    else                { lb = bx - 1568; in = siW2; out = siW2T; R = 256; C = 128; }
    const int txt = C >> 5;
    const int c0 = (lb % txt) << 5;
    const int r0 = (lb / txt) << 5;
    __shared__ float tile[32][33];
    #pragma unroll
    for (int i = 0; i < 4; ++i)
        tile[tx][ty + 8 * i] = in[(size_t)(r0 + ty + 8 * i) * C + c0 + tx];
    __syncthreads();
    #pragma unroll
    for (int i = 0; i < 4; ++i)
        out[(size_t)(c0 + ty + 8 * i) * R + r0 + tx] = (f16)tile[ty + 8 * i][tx];
}

// ---------------- speed_in MLP: sF16[b, 0:128] = relu(speed*W1+b1) @ W2 + b2 ----------------
__global__ __launch_bounds__(256) void speedin_kernel(
    const float* __restrict__ speed,
    const float* __restrict__ siW1, const float* __restrict__ sib1,
    const f16* __restrict__ siW2T, const float* __restrict__ sib2,
    f16* __restrict__ sF16)
{
    __shared__ f16 H[64 * 264];
    __shared__ float spd[64];
    const int tid = threadIdx.x;
    const int rb = blockIdx.x * 64;
    if (tid < 64) spd[tid] = speed[rb + tid];
    __syncthreads();
    {
        const float w1 = siW1[tid];
        const float b1v = sib1[tid];
        #pragma unroll 4
        for (int r = 0; r < 64; ++r) {
            float h = spd[r] * w1 + b1v;
            H[r * 264 + tid] = (f16)(h > 0.f ? h : 0.f);
        }
    }
    __syncthreads();
    const int w = tid >> 6, lane = tid & 63, lq = lane >> 4, l16 = lane & 15;
    const int nb = w * 32;
    f32x4 acc[4][2];
    #pragma unroll
    for (int mt = 0; mt < 4; ++mt)
        #pragma unroll
        for (int nt = 0; nt < 2; ++nt)
            acc[mt][nt] = (f32x4){0.f, 0.f, 0.f, 0.f};
    for (int ks = 0; ks < 8; ++ks) {
        const int koff = ks * 32 + lq * 8;
        f16x8 af[4], bf[2];
        #pragma unroll
        for (int mt = 0; mt < 4; ++mt)
            af[mt] = *(const f16x8*)(&H[(mt * 16 + l16) * 264 + koff]);
        #pragma unroll
        for (int nt = 0; nt < 2; ++nt)
            bf[nt] = *(const f16x8*)(siW2T + (size_t)(nb + nt * 16 + l16) * 256 + koff);
        #pragma unroll
        for (int mt = 0; mt < 4; ++mt)
            #pragma unroll
            for (int nt = 0; nt < 2; ++nt)
                acc[mt][nt] = __builtin_amdgcn_mfma_f32_16x16x32_f16(af[mt], bf[nt], acc[mt][nt], 0, 0, 0);
    }
    #pragma unroll
    for (int mt = 0; mt < 4; ++mt)
        #pragma unroll
        for (int nt = 0; nt < 2; ++nt) {
            const int n = nb + nt * 16 + l16;
            const float bv = sib2[n];
            #pragma unroll
            for (int r2 = 0; r2 < 4; ++r2) {
                const int m = mt * 16 + lq * 4 + r2;
                sF16[(size_t)(rb + m) * 128 + n] = (f16)(acc[mt][nt][r2] + bv);
            }
        }
}

// ---------------- counting sort: histogram -> plan -> place ----------------
__global__ void hist_kernel(const int* __restrict__ cmd, int* __restrict__ counts) {
    __shared__ int h[6];
    const int tid = threadIdx.x;
    if (tid < 6) h[tid] = 0;
    __syncthreads();
    const int i = blockIdx.x * 256 + tid;
    atomicAdd(&h[cmd[i] - 1], 1);
    __syncthreads();
    if (tid < 6) atomicAdd(&counts[tid], h[tid]);
}

__global__ void plan_kernel(const int* __restrict__ counts,
                            int* __restrict__ binBase, int* __restrict__ tile_cmd) {
    if (threadIdx.x == 0 && blockIdx.x == 0) {
        int base = 0, t = 0;
        for (int c = 0; c < 6; ++c) {
            binBase[c] = base;
            const int nt = (counts[c] + 63) >> 6;
            for (int j = 0; j < nt; ++j) tile_cmd[t++] = c;
            base += nt << 6;
        }
        binBase[6] = base;
        while (t < NT_BRANCH) tile_cmd[t++] = -1;
    }
}

__global__ void place_kernel(const int* __restrict__ cmd,
                             const int* __restrict__ binBase,
                             int* __restrict__ cursors, int* __restrict__ perm) {
    __shared__ int lcnt[6], lbase[6];
    const int tid = threadIdx.x;
    if (tid < 6) lcnt[tid] = 0;
    __syncthreads();
    const int i = blockIdx.x * 256 + tid;
    const int c = cmd[i] - 1;
    const int myr = atomicAdd(&lcnt[c], 1);
    __syncthreads();
    if (tid < 6) lbase[tid] = atomicAdd(&cursors[tid], lcnt[tid]);
    __syncthreads();
    perm[binBase[c] + lbase[c] + myr] = i;
}

// ---------------- heads: per-64-row tile, 3-layer MLP fused ----------------
// Blocks [0, NT_BRANCH): branch head (rows via perm, command-uniform tile,
//   sigmoid 3-wide output). Blocks [NT_BRANCH, +NT_SPEED): speed head
//   (identity rows, 1-wide output).
__global__ __launch_bounds__(256, 2) void heads_kernel(
    const float* __restrict__ emb,        // [B,512] fp32
    const f16* __restrict__ sF16,         // [B,128]
    const int* __restrict__ perm,
    const int* __restrict__ tile_cmd,
    const f16* __restrict__ bW1T, const f16* __restrict__ bW2T,
    const float* __restrict__ bW3,
    const float* __restrict__ bb1, const float* __restrict__ bb2,
    const float* __restrict__ bb3,
    const f16* __restrict__ soW1T, const f16* __restrict__ soW2T,
    const float* __restrict__ soW3,
    const float* __restrict__ sob1, const float* __restrict__ sob2,
    const float* __restrict__ sob3,
    float* __restrict__ out)
{
    __shared__ f16 lds[64 * 264];   // A-staging [64][72] aliases h1/h2 [64][264]
    __shared__ int rowIdx[64];
    const int bx = blockIdx.x;
    const int tid = threadIdx.x;
    const bool is_speed = (bx >= NT_BRANCH);
    const f16 *W1T, *W2T;
    const float *W3, *bias1, *bias2, *bias3;
    if (is_speed) {
        const int t = bx - NT_BRANCH;
        if (tid < 64) rowIdx[tid] = t * 64 + tid;
        W1T = soW1T; W2T = soW2T; W3 = soW3;
        bias1 = sob1; bias2 = sob2; bias3 = sob3;
    } else {
        const int c = tile_cmd[bx];
        if (c < 0) return;
        if (tid < 64) rowIdx[tid] = perm[bx * 64 + tid];
        W1T = bW1T + (size_t)c * 256 * 640;
        W2T = bW2T + (size_t)c * 256 * 256;
        W3  = bW3  + (size_t)c * 256 * 3;
        bias1 = bb1 + c * 256; bias2 = bb2 + c * 256; bias3 = bb3 + c * 3;
    }
    const int w = tid >> 6, lane = tid & 63, lq = lane >> 4, l16 = lane & 15;
    const int nb = w * 64;            // wave's 64-col N slice of 256
    f32x4 acc[4][4];
    #pragma unroll
    for (int mt = 0; mt < 4; ++mt)
        #pragma unroll
        for (int nt = 0; nt < 4; ++nt)
            acc[mt][nt] = (f32x4){0.f, 0.f, 0.f, 0.f};

    // GEMM1: K=640 (cols 0-511 from fp32 embedding, 512-639 from sF16)
    for (int kc = 0; kc < 10; ++kc) {
        __syncthreads();
        #pragma unroll
        for (int s = tid; s < 512; s += 256) {
            const int r = s >> 3, g = s & 7;
            int grow = rowIdx[r]; if (grow < 0) grow = 0;
            const int k0 = kc * 64 + g * 8;
            f16x8 v;
            if (k0 < 512) {
                const float* src = emb + (size_t)grow * 512 + k0;
                const float4 p0 = *(const float4*)(src);
                const float4 p1 = *(const float4*)(src + 4);
                v[0] = (f16)p0.x; v[1] = (f16)p0.y; v[2] = (f16)p0.z; v[3] = (f16)p0.w;
                v[4] = (f16)p1.x; v[5] = (f16)p1.y; v[6] = (f16)p1.z; v[7] = (f16)p1.w;
            } else {
                v = *(const f16x8*)(sF16 + (size_t)grow * 128 + (k0 - 512));
            }
            *(f16x8*)(&lds[r * 72 + g * 8]) = v;
        }
        __syncthreads();
        for (int ks = 0; ks < 2; ++ks) {
            const int koff = ks * 32 + lq * 8;
            f16x8 af[4], bf[4];
            #pragma unroll
            for (int mt = 0; mt < 4; ++mt)
                af[mt] = *(const f16x8*)(&lds[(mt * 16 + l16) * 72 + koff]);
            #pragma unroll
            for (int nt = 0; nt < 4; ++nt)
                bf[nt] = *(const f16x8*)(W1T + (size_t)(nb + nt * 16 + l16) * 640 + kc * 64 + koff);
            #pragma unroll
            for (int mt = 0; mt < 4; ++mt)
                #pragma unroll
                for (int nt = 0; nt < 4; ++nt)
                    acc[mt][nt] = __builtin_amdgcn_mfma_f32_16x16x32_f16(af[mt], bf[nt], acc[mt][nt], 0, 0, 0);
        }
    }
    __syncthreads();
    // h1 = relu(acc + b1) -> lds [64][264]
    #pragma unroll
    for (int mt = 0; mt < 4; ++mt)
        #pragma unroll
        for (int nt = 0; nt < 4; ++nt) {
            const int n = nb + nt * 16 + l16;
            const float bv = bias1[n];
            #pragma unroll
            for (int r2 = 0; r2 < 4; ++r2) {
                const int m = mt * 16 + lq * 4 + r2;
                const float v = acc[mt][nt][r2] + bv;
                lds[m * 264 + n] = (f16)(v > 0.f ? v : 0.f);
            }
            acc[mt][nt] = (f32x4){0.f, 0.f, 0.f, 0.f};
        }
    __syncthreads();
    // GEMM2: K=256, A = h1 in LDS (no staging barriers)
    for (int ks = 0; ks < 8; ++ks) {
        const int koff = ks * 32 + lq * 8;
        f16x8 af[4], bf[4];
        #pragma unroll
        for (int mt = 0; mt < 4; ++mt)
            af[mt] = *(const f16x8*)(&lds[(mt * 16 + l16) * 264 + koff]);
        #pragma unroll
        for (int nt = 0; nt < 4; ++nt)
            bf[nt] = *(const f16x8*)(W2T + (size_t)(nb + nt * 16 + l16) * 256 + koff);
        #pragma unroll
        for (int mt = 0; mt < 4; ++mt)
            #pragma unroll
            for (int nt = 0; nt < 4; ++nt)
                acc[mt][nt] = __builtin_amdgcn_mfma_f32_16x16x32_f16(af[mt], bf[nt], acc[mt][nt], 0, 0, 0);
    }
    __syncthreads();
    // h2 = relu(acc + b2) -> lds
    #pragma unroll
    for (int mt = 0; mt < 4; ++mt)
        #pragma unroll
        for (int nt = 0; nt < 4; ++nt) {
            const int n = nb + nt * 16 + l16;
            const float bv = bias2[n];
            #pragma unroll
            for (int r2 = 0; r2 < 4; ++r2) {
                const int m = mt * 16 + lq * 4 + r2;
                const float v = acc[mt][nt][r2] + bv;
                lds[m * 264 + n] = (f16)(v > 0.f ? v : 0.f);
            }
        }
    __syncthreads();
    // GEMM3 (VALU matvec): 4 threads per row, shuffle-reduce, scatter store
    const int r = tid >> 2, p = tid & 3;
    const int grow = rowIdx[r];
    if (!is_speed) {
        float a0 = 0.f, a1 = 0.f, a2 = 0.f;
        #pragma unroll 8
        for (int kk = 0; kk < 64; ++kk) {
            const int k = p * 64 + kk;
            const float h = (float)lds[r * 264 + k];
            a0 += h * W3[k * 3 + 0];
            a1 += h * W3[k * 3 + 1];
            a2 += h * W3[k * 3 + 2];
        }
        a0 += __shfl_xor(a0, 1); a0 += __shfl_xor(a0, 2);
        a1 += __shfl_xor(a1, 1); a1 += __shfl_xor(a1, 2);
        a2 += __shfl_xor(a2, 1); a2 += __shfl_xor(a2, 2);
        if (p == 0 && grow >= 0) {
            out[(size_t)grow * 3 + 0] = 1.f / (1.f + __expf(-(a0 + bias3[0])));
            out[(size_t)grow * 3 + 1] = 1.f / (1.f + __expf(-(a1 + bias3[1])));
            out[(size_t)grow * 3 + 2] = 1.f / (1.f + __expf(-(a2 + bias3[2])));
        }
    } else {
        float a0 = 0.f;
        #pragma unroll 8
        for (int kk = 0; kk < 64; ++kk) {
            const int k = p * 64 + kk;
            a0 += (float)lds[r * 264 + k] * W3[k];
        }
        a0 += __shfl_xor(a0, 1); a0 += __shfl_xor(a0, 2);
        if (p == 0) out[(size_t)3 * B_ROWS + grow] = a0 + bias3[0];
    }
}

extern "C" void kernel_launch(void* const* d_in, const int* in_sizes, int n_in,
                              void* d_out, int out_size, void* d_ws, size_t ws_size,
                              hipStream_t stream) {
    (void)in_sizes; (void)n_in; (void)out_size; (void)ws_size;
    const float* embedding = (const float*)d_in[0];
    const float* speed     = (const float*)d_in[1];
    const int*   command   = (const int*)d_in[2];
    const float* si_W1 = (const float*)d_in[3];
    const float* si_b1 = (const float*)d_in[4];
    const float* si_W2 = (const float*)d_in[5];
    const float* si_b2 = (const float*)d_in[6];
    const float* bW1   = (const float*)d_in[7];
    const float* bb1   = (const float*)d_in[8];
    const float* bW2   = (const float*)d_in[9];
    const float* bb2   = (const float*)d_in[10];
    const float* bW3   = (const float*)d_in[11];
    const float* bb3   = (const float*)d_in[12];
    const float* so_W1 = (const float*)d_in[13];
    const float* so_b1 = (const float*)d_in[14];
    const float* so_W2 = (const float*)d_in[15];
    const float* so_b2 = (const float*)d_in[16];
    const float* so_W3 = (const float*)d_in[17];
    const float* so_b3 = (const float*)d_in[18];
    float* out = (float*)d_out;

    char* ws = (char*)d_ws;
    f16* sF16   = (f16*)(ws + OFF_SF16);
    f16* siW2T  = (f16*)(ws + OFF_SIW2T);
    f16* bW1T   = (f16*)(ws + OFF_BW1T);
    f16* bW2T   = (f16*)(ws + OFF_BW2T);
    f16* soW1T  = (f16*)(ws + OFF_SOW1T);
    f16* soW2T  = (f16*)(ws + OFF_SOW2T);
    int* counts = (int*)(ws + OFF_COUNTS);
    int* cursors= (int*)(ws + OFF_CURSORS);
    int* binBase= (int*)(ws + OFF_BINBASE);
    int* tile_cmd = (int*)(ws + OFF_TILECMD);
    int* perm   = (int*)(ws + OFF_PERM);

    prep_kernel<<<1858, dim3(32, 8), 0, stream>>>(
        si_W2, bW1, bW2, so_W1, so_W2,
        siW2T, bW1T, bW2T, soW1T, soW2T, counts, cursors, perm);
    speedin_kernel<<<1024, 256, 0, stream>>>(speed, si_W1, si_b1, siW2T, si_b2, sF16);
    hist_kernel<<<256, 256, 0, stream>>>(command, counts);
    plan_kernel<<<1, 64, 0, stream>>>(counts, binBase, tile_cmd);
    place_kernel<<<256, 256, 0, stream>>>(command, binBase, cursors, perm);
    heads_kernel<<<NT_BRANCH + NT_SPEED, 256, 0, stream>>>(
        embedding, sF16, perm, tile_cmd,
        bW1T, bW2T, bW3, bb1, bb2, bb3,
        soW1T, soW2T, so_W3, so_b1, so_b2, so_b3, out);
}